// Round 5
// baseline (229.334 us; speedup 1.0000x reference)
//
#include <hip/hip_runtime.h>
#include <math.h>

typedef __bf16 bf16_t;
typedef bf16_t bf16x8 __attribute__((ext_vector_type(8)));
typedef bf16_t bf16x4 __attribute__((ext_vector_type(4)));
typedef float  f32x4  __attribute__((ext_vector_type(4)));

#define MFMA16(a, b, c) __builtin_amdgcn_mfma_f32_16x16x32_bf16(a, b, c, 0, 0, 0)

constexpr float BN_INV = 0.999995000037499687f;  // 1/sqrt(1+1e-5)

// ---------------------------------------------------------------------------
// K1: f = ReLU(BN(W2 @ feature)) -> bf16 table fbf[t][32] (64B rows) and
// xyz4 float4 table. Split tables keep the per-batch gather working set at
// 3.3 MB (< 4 MB per-XCD L2). One wave per 64 points.
// ---------------------------------------------------------------------------
__global__ __launch_bounds__(256) void rfa_k1(
    const float* __restrict__ feature, const float* __restrict__ xyz,
    const float* __restrict__ W2,
    const float* __restrict__ g2, const float* __restrict__ b2,
    bf16_t* __restrict__ fbf, float4* __restrict__ xyz4,
    int N, int nwaves)
{
    int gtid = blockIdx.x * 256 + threadIdx.x;
    int w = gtid >> 6, lane = gtid & 63;
    if (w >= nwaves) return;
    int pt = lane & 15, quad = lane >> 4;
    int T0 = w * 64;
    int b  = T0 / N;
    int n0 = T0 - b * N;

    {
        size_t p = (size_t)T0 + lane;
        xyz4[p] = make_float4(xyz[p * 3], xyz[p * 3 + 1], xyz[p * 3 + 2], 0.f);
    }

    bf16x8 A[2][2];
    #pragma unroll
    for (int mt = 0; mt < 2; ++mt) {
        int h = mt * 16 + pt;
        float sc = g2[h] * BN_INV;
        #pragma unroll
        for (int ks = 0; ks < 2; ++ks) {
            const float* src = W2 + h * 64 + ks * 32 + quad * 8;
            bf16x8 v;
            #pragma unroll
            for (int j = 0; j < 8; ++j) v[j] = (bf16_t)(src[j] * sc);
            A[mt][ks] = v;
        }
    }
    float b2r[8];
    #pragma unroll
    for (int mt = 0; mt < 2; ++mt)
        #pragma unroll
        for (int r = 0; r < 4; ++r) b2r[mt * 4 + r] = b2[mt * 16 + quad * 4 + r];

    const float* fb = feature + (size_t)b * 64 * N;

    #pragma unroll
    for (int g = 0; g < 4; ++g) {
        int nn = n0 + g * 16 + pt;
        size_t T = (size_t)T0 + g * 16 + pt;
        bf16x8 Bf[2];
        #pragma unroll
        for (int ks = 0; ks < 2; ++ks) {
            bf16x8 v;
            #pragma unroll
            for (int j = 0; j < 8; ++j)
                v[j] = (bf16_t)fb[(size_t)(ks * 32 + quad * 8 + j) * N + nn];
            Bf[ks] = v;
        }
        f32x4 acc[2] = {f32x4{0,0,0,0}, f32x4{0,0,0,0}};
        #pragma unroll
        for (int mt = 0; mt < 2; ++mt) {
            acc[mt] = MFMA16(A[mt][0], Bf[0], acc[mt]);
            acc[mt] = MFMA16(A[mt][1], Bf[1], acc[mt]);
        }
        #pragma unroll
        for (int mt = 0; mt < 2; ++mt) {
            bf16x4 o;
            #pragma unroll
            for (int r = 0; r < 4; ++r)
                o[r] = (bf16_t)fmaxf(acc[mt][r] + b2r[mt * 4 + r], 0.f);
            *(bf16x4*)(fbf + T * 32 + mt * 16 + quad * 4) = o;
        }
    }
}

// ---------------------------------------------------------------------------
// K2 (fused final conv): 16 points in MFMA columns, loop over 16 neighbors.
// Batch->XCD affinity: blockIdx%8 selects the XCD (round-robin dispatch
// heuristic); batch b owns XCDs {2b, 2b+1} so each XCD's L2 caches only one
// batch's tables (3.3 MB). One group (16 points) per wave; depth-4 register
// pipeline on the gathers.
// ---------------------------------------------------------------------------
__global__ __launch_bounds__(256) void rfa_k2(
    const bf16_t* __restrict__ fbf, const float4* __restrict__ xyz4,
    const int* __restrict__ nidx,
    const float* __restrict__ W1, const float* __restrict__ g1, const float* __restrict__ b1,
    const float* __restrict__ W3, const float* __restrict__ g3, const float* __restrict__ b3,
    const float* __restrict__ W4, const float* __restrict__ g4, const float* __restrict__ b4,
    float* __restrict__ out, int N)
{
    __shared__ __align__(16) bf16_t sW4[8 * 64 * 8];  // staged W4 A-frags
    __shared__ float sB[4][32 * 18];                   // per-wave bounce [ch][pt]

    int tid = threadIdx.x;
    for (int s = tid; s < 512; s += 256) {
        int f = s >> 6, l = s & 63;
        int mt = f >> 1, ks = f & 1, nn = l & 15, q = l >> 4;
        int o = mt * 16 + nn;
        float sc = g4[o] * BN_INV;
        const float* src = W4 + o * 64 + ks * 32 + q * 8;
        bf16x8 v;
        #pragma unroll
        for (int j = 0; j < 8; ++j) v[j] = (bf16_t)(src[j] * sc);
        *(bf16x8*)(sW4 + s * 8) = v;
    }
    __syncthreads();

    int lane = tid & 63, wv = tid >> 6;
    int n = lane & 15, quad = lane >> 4;

    // batch->XCD affinity decode
    int blk  = blockIdx.x;
    int b    = (blk & 7) >> 1;                    // batch = XCD/2
    int slot = (blk >> 3) * 2 + (blk & 1);        // per-batch block slot
    int grp  = slot * 4 + wv;                     // group within batch
    int nloc = grp * 16;                          // first point of group
    int base = b * N;

    // W3 A-frags (g3-folded), persistent
    bf16x8 A3[2][2];
    #pragma unroll
    for (int mt = 0; mt < 2; ++mt) {
        int h = mt * 16 + n;
        float sc = g3[h] * BN_INV;
        #pragma unroll
        for (int ks = 0; ks < 2; ++ks) {
            const float* src = W3 + h * 64 + ks * 32 + quad * 8;
            bf16x8 v;
            #pragma unroll
            for (int j = 0; j < 8; ++j) v[j] = (bf16_t)(src[j] * sc);
            A3[mt][ks] = v;
        }
    }
    // W1 algebra (channels c = quad*8+j):
    //   fx_c = ReLU( hoist_c + a_c*dist + V_c . nbr ), hoist_c = b1_c + U_c . self
    float a8[8], V0[8], V1[8], V2[8];
    #pragma unroll
    for (int j = 0; j < 8; ++j) {
        int c = quad * 8 + j;
        float s1 = g1[c] * BN_INV;
        const float* wp = W1 + c * 10;
        a8[j] = wp[0] * s1;
        V0[j] = (wp[7] - wp[1]) * s1;
        V1[j] = (wp[8] - wp[2]) * s1;
        V2[j] = (wp[9] - wp[3]) * s1;
    }

    const bf16_t* fb  = fbf  + (size_t)base * 32;
    const float4* xzb = xyz4 + (size_t)base;
    size_t tg = (size_t)base + nloc + n;          // this lane's column point

    float4 ps = xyz4[tg];                          // self xyz (4-dup across quads)
    float hoist[8];
    #pragma unroll
    for (int j = 0; j < 8; ++j) {
        int c = quad * 8 + j;
        float s1 = g1[c] * BN_INV;
        const float* wp = W1 + c * 10;
        hoist[j] = b1[c] + ((wp[1] + wp[4]) * ps.x + (wp[2] + wp[5]) * ps.y +
                            (wp[3] + wp[6]) * ps.z) * s1;
    }

    // neighbor list for this lane's column (quads duplicate, L1-served)
    int j16[16];
    #pragma unroll
    for (int q4 = 0; q4 < 4; ++q4) {
        int4 v = *(const int4*)(nidx + tg * 16 + q4 * 4);
        j16[q4 * 4 + 0] = v.x; j16[q4 * 4 + 1] = v.y;
        j16[q4 * 4 + 2] = v.z; j16[q4 * 4 + 3] = v.w;
    }

    // depth-4 pipelined gather loop
    bf16x8 fj[4]; float4 pn[4];
    #pragma unroll
    for (int s = 0; s < 4; ++s) {
        fj[s] = *(const bf16x8*)(fb + (size_t)j16[s] * 32 + quad * 8);
        pn[s] = xzb[j16[s]];
    }

    f32x4 mx0 = {-3.0e38f, -3.0e38f, -3.0e38f, -3.0e38f};
    f32x4 mx1 = {-3.0e38f, -3.0e38f, -3.0e38f, -3.0e38f};

    #pragma unroll
    for (int k = 0; k < 16; ++k) {
        int s = k & 3;
        float4 p = pn[s];
        bf16x8 Bj = fj[s];

        float rx = ps.x - p.x, ry = ps.y - p.y, rz = ps.z - p.z;
        float dist = sqrtf(rx * rx + ry * ry + rz * rz);

        bf16x8 Bx;
        #pragma unroll
        for (int c = 0; c < 8; ++c) {
            float v = fmaf(a8[c], dist, hoist[c]);
            v = fmaf(V0[c], p.x, v);
            v = fmaf(V1[c], p.y, v);
            v = fmaf(V2[c], p.z, v);
            Bx[c] = (bf16_t)fmaxf(v, 0.f);
        }

        f32x4 ac0 = {0,0,0,0}, ac1 = {0,0,0,0};
        ac0 = MFMA16(A3[0][0], Bj, ac0);
        ac0 = MFMA16(A3[0][1], Bx, ac0);
        ac1 = MFMA16(A3[1][0], Bj, ac1);
        ac1 = MFMA16(A3[1][1], Bx, ac1);
        #pragma unroll
        for (int r = 0; r < 4; ++r) {
            mx0[r] = fmaxf(mx0[r], ac0[r]);
            mx1[r] = fmaxf(mx1[r], ac1[r]);
        }

        if (k + 4 < 16) {
            fj[s] = *(const bf16x8*)(fb + (size_t)j16[k + 4] * 32 + quad * 8);
            pn[s] = xzb[j16[k + 4]];
        }
    }

    // epilogue: bias+ReLU on max, bounce to B-layout, W4 MFMA, store
    float b3r[8];
    #pragma unroll
    for (int mt = 0; mt < 2; ++mt)
        #pragma unroll
        for (int r = 0; r < 4; ++r) b3r[mt * 4 + r] = b3[mt * 16 + quad * 4 + r];

    float* bounce = sB[wv];
    #pragma unroll
    for (int r = 0; r < 4; ++r) {
        bounce[(quad * 4 + r) * 18 + n]      = fmaxf(mx0[r] + b3r[r], 0.f);
        bounce[(16 + quad * 4 + r) * 18 + n] = fmaxf(mx1[r] + b3r[4 + r], 0.f);
    }
    asm volatile("s_waitcnt lgkmcnt(0)" ::: "memory");
    bf16x8 Bm;
    #pragma unroll
    for (int jj = 0; jj < 8; ++jj)
        Bm[jj] = (bf16_t)bounce[(quad * 8 + jj) * 18 + n];

    bf16x8 Bs = *(const bf16x8*)(fb + (size_t)(nloc + n) * 32 + quad * 8);  // f_self

    #pragma unroll
    for (int mt = 0; mt < 4; ++mt) {
        bf16x8 A40 = *(const bf16x8*)(sW4 + ((size_t)(mt * 2 + 0) * 64 + lane) * 8);
        bf16x8 A41 = *(const bf16x8*)(sW4 + ((size_t)(mt * 2 + 1) * 64 + lane) * 8);
        f32x4 acc = {0,0,0,0};
        acc = MFMA16(A40, Bm, acc);
        acc = MFMA16(A41, Bs, acc);
        #pragma unroll
        for (int r = 0; r < 4; ++r) {
            int o = mt * 16 + quad * 4 + r;
            out[((size_t)b * 64 + o) * N + nloc + n] = fmaxf(acc[r] + b4[o], 0.f);
        }
    }
}

// ---------------------------------------------------------------------------
extern "C" void kernel_launch(void* const* d_in, const int* in_sizes, int n_in,
                              void* d_out, int out_size, void* d_ws, size_t ws_size,
                              hipStream_t stream) {
    const float* feature = (const float*)d_in[0];
    const float* xyz     = (const float*)d_in[1];
    const int*   nidx    = (const int*)  d_in[2];
    const float* W1      = (const float*)d_in[3];
    const float* W2      = (const float*)d_in[4];
    const float* W3      = (const float*)d_in[5];
    const float* W4      = (const float*)d_in[6];
    const float* g1 = (const float*)d_in[7];
    const float* b1 = (const float*)d_in[8];
    const float* g2 = (const float*)d_in[9];
    const float* b2 = (const float*)d_in[10];
    const float* g3 = (const float*)d_in[11];
    const float* b3 = (const float*)d_in[12];
    const float* g4 = (const float*)d_in[13];
    const float* b4 = (const float*)d_in[14];
    float* out = (float*)d_out;

    const int B = 4;
    const int N = in_sizes[1] / (B * 3);
    const int total = B * N;                      // 163840

    bf16_t* fbf  = (bf16_t*)d_ws;                 // [total][32] bf16  (10.5 MB)
    float4* xyz4 = (float4*)((char*)d_ws + (size_t)total * 32 * sizeof(bf16_t));

    const int nw1 = total / 64;
    const int blk1 = (nw1 + 3) / 4;
    // k2: one group(16 pts) per wave, 4 waves/block -> total/64 blocks.
    // Requires total/64 divisible by 8 for the XCD decode (2560 here).
    const int blk2 = total / 64;

    rfa_k1<<<blk1, 256, 0, stream>>>(feature, xyz, W2, g2, b2, fbf, xyz4, N, nw1);
    rfa_k2<<<blk2, 256, 0, stream>>>(fbf, xyz4, nidx, W1, g1, b1, W3, g3, b3,
                                     W4, g4, b4, out, N);
}

// Round 6
// 190.670 us; speedup vs baseline: 1.2028x; 1.2028x over previous
//
#include <hip/hip_runtime.h>
#include <math.h>

typedef __bf16 bf16_t;
typedef bf16_t bf16x8 __attribute__((ext_vector_type(8)));
typedef bf16_t bf16x4 __attribute__((ext_vector_type(4)));
typedef float  f32x4  __attribute__((ext_vector_type(4)));

#define MFMA16(a, b, c) __builtin_amdgcn_mfma_f32_16x16x32_bf16(a, b, c, 0, 0, 0)

constexpr float BN_INV = 0.999995000037499687f;  // 1/sqrt(1+1e-5)
constexpr int G2 = 2;  // point-groups (of 16) per wave in k2

// ---------------------------------------------------------------------------
// K1: f = ReLU(BN(W2 @ feature)) -> bf16 table fbf[t][32] (64B rows) and
// xyz4 float4 table. Split tables keep the per-batch gather working set at
// 3.3 MB (< 4 MB per-XCD L2). One wave per 64 points.
// ---------------------------------------------------------------------------
__global__ __launch_bounds__(256) void rfa_k1(
    const float* __restrict__ feature, const float* __restrict__ xyz,
    const float* __restrict__ W2,
    const float* __restrict__ g2, const float* __restrict__ b2,
    bf16_t* __restrict__ fbf, float4* __restrict__ xyz4,
    int N, int nwaves)
{
    int gtid = blockIdx.x * 256 + threadIdx.x;
    int w = gtid >> 6, lane = gtid & 63;
    if (w >= nwaves) return;
    int pt = lane & 15, quad = lane >> 4;
    int T0 = w * 64;
    int b  = T0 / N;
    int n0 = T0 - b * N;

    {
        size_t p = (size_t)T0 + lane;
        xyz4[p] = make_float4(xyz[p * 3], xyz[p * 3 + 1], xyz[p * 3 + 2], 0.f);
    }

    bf16x8 A[2][2];
    #pragma unroll
    for (int mt = 0; mt < 2; ++mt) {
        int h = mt * 16 + pt;
        float sc = g2[h] * BN_INV;
        #pragma unroll
        for (int ks = 0; ks < 2; ++ks) {
            const float* src = W2 + h * 64 + ks * 32 + quad * 8;
            bf16x8 v;
            #pragma unroll
            for (int j = 0; j < 8; ++j) v[j] = (bf16_t)(src[j] * sc);
            A[mt][ks] = v;
        }
    }
    float b2r[8];
    #pragma unroll
    for (int mt = 0; mt < 2; ++mt)
        #pragma unroll
        for (int r = 0; r < 4; ++r) b2r[mt * 4 + r] = b2[mt * 16 + quad * 4 + r];

    const float* fb = feature + (size_t)b * 64 * N;

    #pragma unroll
    for (int g = 0; g < 4; ++g) {
        int nn = n0 + g * 16 + pt;
        size_t T = (size_t)T0 + g * 16 + pt;
        bf16x8 Bf[2];
        #pragma unroll
        for (int ks = 0; ks < 2; ++ks) {
            bf16x8 v;
            #pragma unroll
            for (int j = 0; j < 8; ++j)
                v[j] = (bf16_t)fb[(size_t)(ks * 32 + quad * 8 + j) * N + nn];
            Bf[ks] = v;
        }
        f32x4 acc[2] = {f32x4{0,0,0,0}, f32x4{0,0,0,0}};
        #pragma unroll
        for (int mt = 0; mt < 2; ++mt) {
            acc[mt] = MFMA16(A[mt][0], Bf[0], acc[mt]);
            acc[mt] = MFMA16(A[mt][1], Bf[1], acc[mt]);
        }
        #pragma unroll
        for (int mt = 0; mt < 2; ++mt) {
            bf16x4 o;
            #pragma unroll
            for (int r = 0; r < 4; ++r)
                o[r] = (bf16_t)fmaxf(acc[mt][r] + b2r[mt * 4 + r], 0.f);
            *(bf16x4*)(fbf + T * 32 + mt * 16 + quad * 4) = o;
        }
    }
}

// ---------------------------------------------------------------------------
// K2 (fused final conv): 16 points in MFMA columns, loop over 16 neighbors.
// Batch->XCD affinity (blockIdx%8 ~ XCD; batch b owns XCDs {2b,2b+1}) keeps
// each XCD's gather working set at 3.3 MB -> L2-resident (proven: FETCH
// 129->28 MB in R5). G2=2 groups per wave restores setup amortization;
// depth-2 pipeline keeps VGPR ~116 -> 4 waves/SIMD.
// ---------------------------------------------------------------------------
__global__ __launch_bounds__(256) void rfa_k2(
    const bf16_t* __restrict__ fbf, const float4* __restrict__ xyz4,
    const int* __restrict__ nidx,
    const float* __restrict__ W1, const float* __restrict__ g1, const float* __restrict__ b1,
    const float* __restrict__ W3, const float* __restrict__ g3, const float* __restrict__ b3,
    const float* __restrict__ W4, const float* __restrict__ g4, const float* __restrict__ b4,
    float* __restrict__ out, int N)
{
    __shared__ __align__(16) bf16_t sW4[8 * 64 * 8];  // staged W4 A-frags
    __shared__ float sB[4][32 * 18];                   // per-wave bounce [ch][pt]

    int tid = threadIdx.x;
    for (int s = tid; s < 512; s += 256) {
        int f = s >> 6, l = s & 63;
        int mt = f >> 1, ks = f & 1, nn = l & 15, q = l >> 4;
        int o = mt * 16 + nn;
        float sc = g4[o] * BN_INV;
        const float* src = W4 + o * 64 + ks * 32 + q * 8;
        bf16x8 v;
        #pragma unroll
        for (int j = 0; j < 8; ++j) v[j] = (bf16_t)(src[j] * sc);
        *(bf16x8*)(sW4 + s * 8) = v;
    }
    __syncthreads();

    int lane = tid & 63, wv = tid >> 6;
    int n = lane & 15, quad = lane >> 4;

    // batch->XCD affinity decode: per-batch 320 blocks, 8 groups per block
    int blk   = blockIdx.x;
    int b     = (blk & 7) >> 1;                   // batch = XCD/2
    int slot  = (blk >> 3) * 2 + (blk & 1);       // per-batch block slot [0,320)
    int grp0  = slot * (4 * G2) + wv * G2;        // first group of this wave
    int base  = b * N;

    // W3 A-frags (g3-folded), persistent
    bf16x8 A3[2][2];
    #pragma unroll
    for (int mt = 0; mt < 2; ++mt) {
        int h = mt * 16 + n;
        float sc = g3[h] * BN_INV;
        #pragma unroll
        for (int ks = 0; ks < 2; ++ks) {
            const float* src = W3 + h * 64 + ks * 32 + quad * 8;
            bf16x8 v;
            #pragma unroll
            for (int j = 0; j < 8; ++j) v[j] = (bf16_t)(src[j] * sc);
            A3[mt][ks] = v;
        }
    }
    // W1 algebra (channels c = quad*8+j):
    //   fx_c = ReLU( hoist_c + a_c*dist + V_c . nbr ), hoist_c = b1_c + U_c . self
    float a8[8], V0[8], V1[8], V2[8];
    #pragma unroll
    for (int j = 0; j < 8; ++j) {
        int c = quad * 8 + j;
        float s1 = g1[c] * BN_INV;
        const float* wp = W1 + c * 10;
        a8[j] = wp[0] * s1;
        V0[j] = (wp[7] - wp[1]) * s1;
        V1[j] = (wp[8] - wp[2]) * s1;
        V2[j] = (wp[9] - wp[3]) * s1;
    }
    float b3r[8];
    #pragma unroll
    for (int mt = 0; mt < 2; ++mt)
        #pragma unroll
        for (int r = 0; r < 4; ++r) b3r[mt * 4 + r] = b3[mt * 16 + quad * 4 + r];

    const bf16_t* fb  = fbf  + (size_t)base * 32;
    const float4* xzb = xyz4 + (size_t)base;
    float* bounce = sB[wv];

    for (int gi = 0; gi < G2; ++gi) {
        int grp  = grp0 + gi;
        int nloc = grp * 16;
        size_t tg = (size_t)base + nloc + n;      // this lane's column point

        float4 ps = xyz4[tg];                     // self xyz (4-dup across quads)
        float hoist[8];
        #pragma unroll
        for (int j = 0; j < 8; ++j) {
            int c = quad * 8 + j;
            float s1 = g1[c] * BN_INV;
            const float* wp = W1 + c * 10;
            hoist[j] = b1[c] + ((wp[1] + wp[4]) * ps.x + (wp[2] + wp[5]) * ps.y +
                                (wp[3] + wp[6]) * ps.z) * s1;
        }

        // neighbor list for this lane's column (quads duplicate, L1-served)
        int j16[16];
        #pragma unroll
        for (int q4 = 0; q4 < 4; ++q4) {
            int4 v = *(const int4*)(nidx + tg * 16 + q4 * 4);
            j16[q4 * 4 + 0] = v.x; j16[q4 * 4 + 1] = v.y;
            j16[q4 * 4 + 2] = v.z; j16[q4 * 4 + 3] = v.w;
        }

        // depth-2 pipelined gather loop
        bf16x8 fj[2]; float4 pn[2];
        {
            fj[0] = *(const bf16x8*)(fb + (size_t)j16[0] * 32 + quad * 8);
            pn[0] = xzb[j16[0]];
            fj[1] = *(const bf16x8*)(fb + (size_t)j16[1] * 32 + quad * 8);
            pn[1] = xzb[j16[1]];
        }

        f32x4 mx0 = {-3.0e38f, -3.0e38f, -3.0e38f, -3.0e38f};
        f32x4 mx1 = {-3.0e38f, -3.0e38f, -3.0e38f, -3.0e38f};

        #pragma unroll
        for (int k = 0; k < 16; ++k) {
            int s = k & 1;
            float4 p = pn[s];
            bf16x8 Bj = fj[s];

            float rx = ps.x - p.x, ry = ps.y - p.y, rz = ps.z - p.z;
            float dist = sqrtf(rx * rx + ry * ry + rz * rz);

            bf16x8 Bx;
            #pragma unroll
            for (int c = 0; c < 8; ++c) {
                float v = fmaf(a8[c], dist, hoist[c]);
                v = fmaf(V0[c], p.x, v);
                v = fmaf(V1[c], p.y, v);
                v = fmaf(V2[c], p.z, v);
                Bx[c] = (bf16_t)fmaxf(v, 0.f);
            }

            f32x4 ac0 = {0,0,0,0}, ac1 = {0,0,0,0};
            ac0 = MFMA16(A3[0][0], Bj, ac0);
            ac0 = MFMA16(A3[0][1], Bx, ac0);
            ac1 = MFMA16(A3[1][0], Bj, ac1);
            ac1 = MFMA16(A3[1][1], Bx, ac1);
            #pragma unroll
            for (int r = 0; r < 4; ++r) {
                mx0[r] = fmaxf(mx0[r], ac0[r]);
                mx1[r] = fmaxf(mx1[r], ac1[r]);
            }

            if (k + 2 < 16) {
                fj[s] = *(const bf16x8*)(fb + (size_t)j16[k + 2] * 32 + quad * 8);
                pn[s] = xzb[j16[k + 2]];
            }
        }

        // epilogue: bias+ReLU on max, bounce to B-layout, W4 MFMA, store
        #pragma unroll
        for (int r = 0; r < 4; ++r) {
            bounce[(quad * 4 + r) * 18 + n]      = fmaxf(mx0[r] + b3r[r], 0.f);
            bounce[(16 + quad * 4 + r) * 18 + n] = fmaxf(mx1[r] + b3r[4 + r], 0.f);
        }
        asm volatile("s_waitcnt lgkmcnt(0)" ::: "memory");
        bf16x8 Bm;
        #pragma unroll
        for (int jj = 0; jj < 8; ++jj)
            Bm[jj] = (bf16_t)bounce[(quad * 8 + jj) * 18 + n];

        bf16x8 Bs = *(const bf16x8*)(fb + (size_t)(nloc + n) * 32 + quad * 8);  // f_self

        #pragma unroll
        for (int mt = 0; mt < 4; ++mt) {
            bf16x8 A40 = *(const bf16x8*)(sW4 + ((size_t)(mt * 2 + 0) * 64 + lane) * 8);
            bf16x8 A41 = *(const bf16x8*)(sW4 + ((size_t)(mt * 2 + 1) * 64 + lane) * 8);
            f32x4 acc = {0,0,0,0};
            acc = MFMA16(A40, Bm, acc);
            acc = MFMA16(A41, Bs, acc);
            #pragma unroll
            for (int r = 0; r < 4; ++r) {
                int o = mt * 16 + quad * 4 + r;
                out[((size_t)b * 64 + o) * N + nloc + n] = fmaxf(acc[r] + b4[o], 0.f);
            }
        }
        asm volatile("s_waitcnt lgkmcnt(0)" ::: "memory");  // drain before next group's bounce
    }
}

// ---------------------------------------------------------------------------
extern "C" void kernel_launch(void* const* d_in, const int* in_sizes, int n_in,
                              void* d_out, int out_size, void* d_ws, size_t ws_size,
                              hipStream_t stream) {
    const float* feature = (const float*)d_in[0];
    const float* xyz     = (const float*)d_in[1];
    const int*   nidx    = (const int*)  d_in[2];
    const float* W1      = (const float*)d_in[3];
    const float* W2      = (const float*)d_in[4];
    const float* W3      = (const float*)d_in[5];
    const float* W4      = (const float*)d_in[6];
    const float* g1 = (const float*)d_in[7];
    const float* b1 = (const float*)d_in[8];
    const float* g2 = (const float*)d_in[9];
    const float* b2 = (const float*)d_in[10];
    const float* g3 = (const float*)d_in[11];
    const float* b3 = (const float*)d_in[12];
    const float* g4 = (const float*)d_in[13];
    const float* b4 = (const float*)d_in[14];
    float* out = (float*)d_out;

    const int B = 4;
    const int N = in_sizes[1] / (B * 3);
    const int total = B * N;                      // 163840

    bf16_t* fbf  = (bf16_t*)d_ws;                 // [total][32] bf16  (10.5 MB)
    float4* xyz4 = (float4*)((char*)d_ws + (size_t)total * 32 * sizeof(bf16_t));

    const int nw1 = total / 64;
    const int blk1 = (nw1 + 3) / 4;
    // k2: 4 waves * G2 groups of 16 points per block -> total/(64*G2) blocks.
    // Must be divisible by 8 for the XCD-affinity decode (1280 here).
    const int blk2 = total / (64 * G2);

    rfa_k1<<<blk1, 256, 0, stream>>>(feature, xyz, W2, g2, b2, fbf, xyz4, N, nw1);
    rfa_k2<<<blk2, 256, 0, stream>>>(fbf, xyz4, nidx, W1, g1, b1, W3, g3, b3,
                                     W4, g4, b4, out, N);
}